// Round 15
// baseline (157.976 us; speedup 1.0000x reference)
//
#include <hip/hip_runtime.h>

// GCN 2-layer, N=100k, E=3.2M, IN=2, HID=64, OUT=1 (all float32).
// R15 = R14 base (157.8us; 512 buckets x 196 nodes, staged counting sort ->
// hist+dinv,y -> s1+MLP->t -> s2+out; memset'd relative cursors; 16B-aligned
// bucket segments) + 4-WAY PRIVATIZED LDS accumulators in the three scan
// kernels: R14 had 1024 threads atomically hitting 196 counters (~5-way
// same-address contention, ~1.6-3x LDS-pipe penalty per m136 data); giving
// each 256-thread group its own copy cuts contention to ~1.3-way (free),
// reduced at the end (4 adds/node). Sort untouched (2-way, already free).

#define NBUCK 512
#define BSH   196        // nodes per bucket (512*196 = 100352 >= n)
#define RBITS 17         // row bits (n < 131072)
#define RMASK ((1 << RBITS) - 1)
#define CAP   6752       // packed ints per bucket (mean 6250, +6.3 sigma), %4==0
#define SORTB 512
#define SCAPS 24         // staging per (block,bucket): mean 12.2, +3.4 sigma
#define TPS   1024
#define TPB   1024
#define NCP   4          // privatized accumulator copies (256 threads each)

__device__ __forceinline__ void sort_one(int c, int r, int* fill, int* stage,
                                         int* __restrict__ gcur,
                                         int* __restrict__ packed) {
    int b = (int)((unsigned)c / (unsigned)BSH);   // magic-mul div by 196
    int l = c - b * BSH;
    int w = (l << RBITS) | r;
    int p = atomicAdd(&fill[b], 1);
    if (p < SCAPS) stage[b * SCAPS + p] = w;
    else packed[b * CAP + atomicAdd(&gcur[b], 1)] = w;  // rare spill (rel cursor)
}

// staged counting sort by dest bucket: packed[b-region] gets ((lcol<<17)|row)
__global__ void __launch_bounds__(TPS)
k_sort(const int* __restrict__ row, const int* __restrict__ col,
       int* __restrict__ gcur, int* __restrict__ packed, int E) {
    __shared__ int fill[NBUCK];
    __shared__ int gb[NBUCK];
    __shared__ int stage[NBUCK * SCAPS];   // 49 KB
    const int tid = threadIdx.x, bid = blockIdx.x;
    for (int i = tid; i < NBUCK; i += TPS) fill[i] = 0;
    __syncthreads();
    const int q = E >> 2;
    const int q0 = (int)((long long)bid * q / SORTB);
    const int q1 = (int)((long long)(bid + 1) * q / SORTB);
    const int4* c4 = (const int4*)col;
    const int4* r4 = (const int4*)row;
    for (int i = q0 + tid; i < q1; i += TPS) {
        int4 c = c4[i], r = r4[i];
        sort_one(c.x, r.x, fill, stage, gcur, packed);
        sort_one(c.y, r.y, fill, stage, gcur, packed);
        sort_one(c.z, r.z, fill, stage, gcur, packed);
        sort_one(c.w, r.w, fill, stage, gcur, packed);
    }
    if (bid == SORTB - 1)   // tail if E % 4 != 0
        for (int e = (q << 2) + tid; e < E; e += TPS)
            sort_one(col[e], row[e], fill, stage, gcur, packed);
    __syncthreads();
    for (int b = tid; b < NBUCK; b += TPS)
        gb[b] = b * CAP + atomicAdd(&gcur[b], min(fill[b], SCAPS));
    __syncthreads();
    const int wid = tid >> 6, lane = tid & 63;
    for (int b = wid; b < NBUCK; b += (TPS >> 6)) {  // per-wave coalesced copy-out
        int cnt = min(fill[b], SCAPS);               // cnt <= 24 < wave
        if (lane < cnt) packed[gb[b] + lane] = stage[b * SCAPS + lane];
    }
}

// hist + epilogue: deg -> dinv; y = dinv*x   (one block = one whole bucket)
__global__ void __launch_bounds__(TPB)
k_h1(const int* __restrict__ gcur, const int* __restrict__ packed,
     const float2* __restrict__ x, float* __restrict__ dinv,
     float2* __restrict__ y, int n) {
    __shared__ int s[NCP * BSH];
    const int b = blockIdx.x;
    const int cp = (threadIdx.x >> 8) * BSH;   // 4 copies, 256 threads each
    for (int i = threadIdx.x; i < NCP * BSH; i += TPB) s[i] = 0;
    __syncthreads();
    const int base = b * CAP;
    const int len = gcur[b];
    const int q = len >> 2;
    const int4* p4 = (const int4*)(packed + base);
    for (int i = threadIdx.x; i < q; i += TPB) {
        int4 w = p4[i];
        atomicAdd(&s[cp + (w.x >> RBITS)], 1);
        atomicAdd(&s[cp + (w.y >> RBITS)], 1);
        atomicAdd(&s[cp + (w.z >> RBITS)], 1);
        atomicAdd(&s[cp + (w.w >> RBITS)], 1);
    }
    for (int e = (q << 2) + threadIdx.x; e < len; e += TPB)
        atomicAdd(&s[cp + (packed[base + e] >> RBITS)], 1);
    __syncthreads();
    if (threadIdx.x < BSH) {
        int i = b * BSH + threadIdx.x;
        if (i < n) {
            int deg = 1 + s[threadIdx.x] + s[BSH + threadIdx.x]
                        + s[2 * BSH + threadIdx.x] + s[3 * BSH + threadIdx.x];
            float d = rsqrtf((float)deg);
            dinv[i] = d;
            float2 xv = x[i];
            y[i] = make_float2(d * xv.x, d * xv.y);
        }
    }
}

// s1 + MLP epilogue: agg = sum y[row]; t = dinv*(relu((dinv*(agg+y))@W1+b1)@W2)
__global__ void __launch_bounds__(TPB)
k_sc1(const int* __restrict__ gcur, const int* __restrict__ packed,
      const float2* __restrict__ y, const float* __restrict__ dinv,
      const float* __restrict__ W1, const float* __restrict__ B1,
      const float* __restrict__ W2, float* __restrict__ t, int n) {
    __shared__ float2 s[NCP * BSH];
    __shared__ float w1a[64], w1b[64], bb1[64], w2[64];
    if (threadIdx.x >= 800 && threadIdx.x < 864) {
        int h = threadIdx.x - 800;
        w1a[h] = W1[h];
        w1b[h] = W1[64 + h];
        bb1[h] = B1[h];
        w2[h]  = W2[h];
    }
    for (int i = threadIdx.x; i < NCP * BSH; i += TPB) s[i] = make_float2(0.f, 0.f);
    __syncthreads();
    const int b = blockIdx.x;
    const int cp = (threadIdx.x >> 8) * BSH;
    const int base = b * CAP;
    const int len = gcur[b];
    const int q = len >> 2;
    const int4* p4 = (const int4*)(packed + base);
    for (int i = threadIdx.x; i < q; i += TPB) {
        int4 w = p4[i];
        float2 v; float* sp;
        v = y[w.x & RMASK]; sp = (float*)&s[cp + (w.x >> RBITS)];
        atomicAdd(sp, v.x); atomicAdd(sp + 1, v.y);
        v = y[w.y & RMASK]; sp = (float*)&s[cp + (w.y >> RBITS)];
        atomicAdd(sp, v.x); atomicAdd(sp + 1, v.y);
        v = y[w.z & RMASK]; sp = (float*)&s[cp + (w.z >> RBITS)];
        atomicAdd(sp, v.x); atomicAdd(sp + 1, v.y);
        v = y[w.w & RMASK]; sp = (float*)&s[cp + (w.w >> RBITS)];
        atomicAdd(sp, v.x); atomicAdd(sp + 1, v.y);
    }
    for (int e = (q << 2) + threadIdx.x; e < len; e += TPB) {
        int w = packed[base + e];
        float2 v = y[w & RMASK];
        float* sp = (float*)&s[cp + (w >> RBITS)];
        atomicAdd(sp, v.x); atomicAdd(sp + 1, v.y);
    }
    __syncthreads();
    if (threadIdx.x < BSH) {
        int i = b * BSH + threadIdx.x;
        if (i < n) {
            float2 a = s[threadIdx.x], c1 = s[BSH + threadIdx.x],
                   c2 = s[2 * BSH + threadIdx.x], c3 = s[3 * BSH + threadIdx.x];
            float gx = (a.x + c1.x) + (c2.x + c3.x);
            float gy = (a.y + c1.y) + (c2.y + c3.y);
            float d = dinv[i];
            float2 yv = y[i];
            float a0 = d * (gx + yv.x);
            float a1 = d * (gy + yv.y);
            float acc = 0.f;
#pragma unroll
            for (int h = 0; h < 64; ++h) {
                float v = fmaf(a0, w1a[h], fmaf(a1, w1b[h], bb1[h]));
                acc = fmaf(fmaxf(v, 0.f), w2[h], acc);
            }
            t[i] = d * acc;
        }
    }
}

// s2 + output epilogue: o = sum t[row]; out = dinv*(o + t_self) + b2
__global__ void __launch_bounds__(TPB)
k_sc2(const int* __restrict__ gcur, const int* __restrict__ packed,
      const float* __restrict__ t, const float* __restrict__ dinv,
      const float* __restrict__ B2, float* __restrict__ out, int n) {
    __shared__ float s[NCP * BSH];
    const int b = blockIdx.x;
    const int cp = (threadIdx.x >> 8) * BSH;
    for (int i = threadIdx.x; i < NCP * BSH; i += TPB) s[i] = 0.f;
    __syncthreads();
    const int base = b * CAP;
    const int len = gcur[b];
    const int q = len >> 2;
    const int4* p4 = (const int4*)(packed + base);
    for (int i = threadIdx.x; i < q; i += TPB) {
        int4 w = p4[i];
        atomicAdd(&s[cp + (w.x >> RBITS)], t[w.x & RMASK]);
        atomicAdd(&s[cp + (w.y >> RBITS)], t[w.y & RMASK]);
        atomicAdd(&s[cp + (w.z >> RBITS)], t[w.z & RMASK]);
        atomicAdd(&s[cp + (w.w >> RBITS)], t[w.w & RMASK]);
    }
    for (int e = (q << 2) + threadIdx.x; e < len; e += TPB) {
        int w = packed[base + e];
        atomicAdd(&s[cp + (w >> RBITS)], t[w & RMASK]);
    }
    __syncthreads();
    if (threadIdx.x < BSH) {
        int i = b * BSH + threadIdx.x;
        if (i < n) {
            float o = (s[threadIdx.x] + s[BSH + threadIdx.x])
                    + (s[2 * BSH + threadIdx.x] + s[3 * BSH + threadIdx.x]);
            out[i] = fmaf(dinv[i], o + t[i], B2[0]);
        }
    }
}

extern "C" void kernel_launch(void* const* d_in, const int* in_sizes, int n_in,
                              void* d_out, int out_size, void* d_ws, size_t ws_size,
                              hipStream_t stream) {
    const float* x  = (const float*)d_in[0];
    const int*   ei = (const int*)d_in[1];
    const float* W1 = (const float*)d_in[2];
    const float* B1 = (const float*)d_in[3];
    const float* W2 = (const float*)d_in[4];
    const float* B2 = (const float*)d_in[5];
    float* out = (float*)d_out;

    const int n = in_sizes[0] / 2;      // 100,000
    const int E = in_sizes[1] / 2;      // 3,200,000
    const int* row = ei;
    const int* col = ei + E;

    // ws: dinv[n] | y[n](f2) | t[n] | gcur[512] | packed[512*CAP ~13.8MB]
    char* ws = (char*)d_ws;
    size_t off = 0;
    float*  dinv = (float*)(ws + off);  off += (size_t)n * 4;
    float2* y    = (float2*)(ws + off); off += (size_t)n * 8;
    float*  t    = (float*)(ws + off);  off += (size_t)n * 4;
    off = (off + 255) & ~(size_t)255;
    int* gcur    = (int*)(ws + off);    off += (size_t)NBUCK * 4;
    off = (off + 255) & ~(size_t)255;
    int* packed  = (int*)(ws + off);

    hipMemsetAsync(gcur, 0, (size_t)NBUCK * 4, stream);   // relative cursors
    k_sort<<<SORTB, TPS, 0, stream>>>(row, col, gcur, packed, E);
    k_h1  <<<NBUCK, TPB, 0, stream>>>(gcur, packed, (const float2*)x, dinv, y, n);
    k_sc1 <<<NBUCK, TPB, 0, stream>>>(gcur, packed, y, dinv, W1, B1, W2, t, n);
    k_sc2 <<<NBUCK, TPB, 0, stream>>>(gcur, packed, t, dinv, B2, out, n);
}